// Round 3
// baseline (2128.177 us; speedup 1.0000x reference)
//
#include <hip/hip_runtime.h>
#include <math.h>

#define T_STEPS 50
#define NT 1024

// workspace layout (float offsets)
#define WS_FC1T 0          // 1600*256 = 409600  : fc1_w transposed [k][j]
#define WS_W2F  409600     // 32*9*64*4 = 73728  : folded conv2, tap-quad-major [ic][q][oc][4]
#define WS_W1F  483328     // 36*64    = 2304    : folded conv1 [j][oc*2+ic]
#define WS_TOTAL 485632

// LDS layout (float offsets)
#define L_XT    0          // 2048
#define L_SPK1  2048       // 32 planes, stride 228 = 7296
#define L_RED   9344       // 8*1600 = 12800
#define L_WOUT  22144      // 2816
#define L_LIST  24960      // 1600 (ints)
#define L_FLAG  26560      // 448
#define L_CNT   27008      // 16 (pad)
#define L_VC1   27024      // 6272 : conv1 membrane, [py*14+px]*32 + oc
#define L_VC2   33296      // 1600
#define L_BN2   34896      // 192 : s2 | sh2 | b2
#define L_IPART2 35088     // 4096 : fc1 partials, 16 wave-groups x 256
#define L_FCP   39184      // 768 : alpha | rho | beta_a (256 each)
#define L_FCS   39952      // 768 : vfc | afc | spf (256 each)
#define L_TOTALF 40720     // 162880 B <= 163840 (160 KiB)
#define SMEM_BYTES (L_TOTALF * 4)

__global__ void prep_kernel(const float* __restrict__ conv1_w,
                            const float* __restrict__ conv2_w,
                            const float* __restrict__ fc1_w,
                            float* __restrict__ ws) {
  int i = blockIdx.x * blockDim.x + threadIdx.x;
  if (i < 409600) {
    int k = i >> 8, j = i & 255;
    ws[WS_FC1T + i] = fc1_w[j * 1600 + k];
  } else if (i < 409600 + 73728) {
    // tap-quad-major layout: index = ((ic*9 + q)*64 + oc)*4 + r, tap jj = 4q + r.
    int i2 = i - 409600;
    int r  = i2 & 3;
    int t2 = i2 >> 2;
    int oc = t2 & 63;
    int t3 = t2 >> 6;      // ic*9 + q
    int q  = t3 % 9;
    int ic = t3 / 9;
    int jj = q * 4 + r, u = jj / 6, v = jj % 6;
    float s = 0.f;
    for (int dy = 0; dy < 2; ++dy) {
      int ky = u - dy; if (ky < 0 || ky > 4) continue;
      for (int dx = 0; dx < 2; ++dx) {
        int kx = v - dx; if (kx < 0 || kx > 4) continue;
        s += conv2_w[((oc * 32 + ic) * 5 + ky) * 5 + kx];
      }
    }
    ws[WS_W2F + i2] = 0.25f * s;
  } else if (i < WS_TOTAL) {
    int i3 = i - 483328;
    int jj = i3 >> 6, l = i3 & 63, oc = l >> 1, ic = l & 1, u = jj / 6, v = jj % 6;
    float s = 0.f;
    for (int dy = 0; dy < 2; ++dy) {
      int ky = u - dy; if (ky < 0 || ky > 4) continue;
      for (int dx = 0; dx < 2; ++dx) {
        int kx = v - dx; if (kx < 0 || kx > 4) continue;
        s += conv1_w[((oc * 2 + ic) * 5 + ky) * 5 + kx];
      }
    }
    ws[WS_W1F + i3] = 0.25f * s;
  }
}

// conv2 half-wave body: rows iy in [IYLO,IYHI], outputs py in [PYLO,PYHI].
#define CONV2_BODY(IYLO, IYHI, PYLO, PYHI)                                   \
  for (int ib = 0; ib < 4; ++ib) {                                           \
    const int ic = g + 8 * ib;                                               \
    const float* fl = &sm[L_FLAG + ic * 14];                                 \
    float fsum = 0.f;                                                        \
    _Pragma("unroll")                                                        \
    for (int iy = IYLO; iy <= IYHI; ++iy) fsum += fl[iy];                    \
    if (fsum != 0.f) {                                                       \
      float w[36];                                                           \
      {                                                                      \
        const float4* wp = ((const float4*)w2f) + (ic * 9) * 64 + lane;      \
        _Pragma("unroll")                                                    \
        for (int q = 0; q < 9; ++q) {                                        \
          float4 f = wp[q * 64];                                             \
          w[4*q] = f.x; w[4*q+1] = f.y; w[4*q+2] = f.z; w[4*q+3] = f.w;      \
        }                                                                    \
      }                                                                      \
      const float* srow = &sm[L_SPK1 + ic * 228];                            \
      _Pragma("unroll")                                                      \
      for (int iy = IYLO; iy <= IYHI; ++iy) {                                \
        if (fl[iy] != 0.f) {                                                 \
          float row[16];                                                     \
          const float4* rp = (const float4*)&srow[iy * 16];                  \
          _Pragma("unroll")                                                  \
          for (int q = 0; q < 4; ++q) {                                      \
            float4 f = rp[q];                                                \
            row[4*q] = f.x; row[4*q+1] = f.y; row[4*q+2] = f.z; row[4*q+3] = f.w; \
          }                                                                  \
          _Pragma("unroll")                                                  \
          for (int py = PYLO; py <= PYHI; ++py) {                            \
            const int u = iy - 2 * py;                                       \
            if (u >= 0 && u <= 5) {                                          \
              _Pragma("unroll")                                              \
              for (int v = 0; v < 6; ++v) {                                  \
                float wv = w[u * 6 + v];                                     \
                _Pragma("unroll")                                            \
                for (int px = 0; px < 5; ++px)                               \
                  acc[(py - PYLO) * 5 + px] += row[2*px + v] * wv;           \
              }                                                              \
            }                                                                \
          }                                                                  \
        }                                                                    \
      }                                                                      \
    }                                                                        \
  }

// block = 1024 (16 waves). LDS 162.9KB -> 1 WG/CU = 4 waves/EU (VGPR cap 128,
// which is what the allocator already chose at 8 waves). The 8-wave config was
// latency-bound: ~21K of 37.7K cycles/step were exposed stalls with only
// 2 waves/SIMD to overlap them. 16 waves doubles latency hiding and balances
// phase 2 (one conv1 row per wave) and phase 3 (py-split half-waves).
__global__ __launch_bounds__(NT, 4) void snn_kernel(
    const float* __restrict__ x,
    const float* __restrict__ bn1_gamma, const float* __restrict__ bn1_beta,
    const float* __restrict__ bn1_mean,  const float* __restrict__ bn1_var,
    const float* __restrict__ bn2_gamma, const float* __restrict__ bn2_beta,
    const float* __restrict__ bn2_mean,  const float* __restrict__ bn2_var,
    const float* __restrict__ beta_c1_raw, const float* __restrict__ beta_c2_raw,
    const float* __restrict__ alpha_raw, const float* __restrict__ rho_raw,
    const float* __restrict__ beta_a_p,  const float* __restrict__ fc_out_w,
    const float* __restrict__ beta_out_p,
    const float* __restrict__ ws, float* __restrict__ out)
{
  extern __shared__ float sm[];
  int* listI = (int*)&sm[L_LIST];
  int* cntI  = (int*)&sm[L_CNT];
  const int tid = threadIdx.x, wave = tid >> 6, lane = tid & 63;
  const int b = blockIdx.x;

  // one-time LDS staging + state zero-init
  for (int i = tid; i < 2816; i += NT) sm[L_WOUT + i] = fc_out_w[i];
  for (int i = tid; i < 6272; i += NT) sm[L_VC1 + i] = 0.f;
  for (int i = tid; i < 1600; i += NT) sm[L_VC2 + i] = 0.f;
  if (tid < 256) {
    // fc params+state in LDS: only wave 0 touches them, keeps them out of the
    // per-wave register budget.
    sm[L_FCP + tid]       = 1.f / (1.f + expf(-alpha_raw[tid]));
    sm[L_FCP + 256 + tid] = 1.f / (1.f + expf(-rho_raw[tid]));
    sm[L_FCP + 512 + tid] = beta_a_p[tid];
    sm[L_FCS + tid] = 0.f;
    sm[L_FCS + 256 + tid] = 0.f;
    sm[L_FCS + 512 + tid] = 0.f;
  }
  if (tid < 64) {
    float s2 = bn2_gamma[tid] / sqrtf(bn2_var[tid] + 1e-5f);
    sm[L_BN2 + tid]       = s2;
    sm[L_BN2 + 64 + tid]  = bn2_beta[tid] - bn2_mean[tid] * s2;
    sm[L_BN2 + 128 + tid] = 1.f / (1.f + expf(-beta_c2_raw[tid]));
  }

  // conv1 lane mapping: lane = oc*2 + ic
  const int oc1 = lane >> 1, ic1 = lane & 1;
  const float s1v  = bn1_gamma[oc1] / sqrtf(bn1_var[oc1] + 1e-5f);
  const float sh1v = bn1_beta[oc1] - bn1_mean[oc1] * s1v;
  const float b1v  = 1.f / (1.f + expf(-beta_c1_raw[oc1]));
  const float beta_o = 1.f / (1.f + expf(-beta_out_p[0]));

  // conv1 weights: persistent in registers (36 regs; only waves 0-13 use them)
  float w1r[36];
  #pragma unroll
  for (int j = 0; j < 36; ++j) w1r[j] = ws[WS_W1F + j * 64 + lane];

  float v_out = 0.f, o_sum = 0.f;  // wave0, lane<11

  const float* xbase = x + (size_t)b * T_STEPS * 2048;
  const float* w2f  = ws + WS_W2F;
  const float* fc1T = ws + WS_FC1T;

  float2 xpre = ((const float2*)xbase)[tid];   // prefetch t=0 (1024 thr x 8B = 8KB)

  __syncthreads();

  for (int t = 0; t < T_STEPS; ++t) {
    // ---- phase 1: commit prefetched x_t to LDS ----
    ((float2*)&sm[L_XT])[tid] = xpre;
    __syncthreads();                                     // barrier A
    {
      int tn = (t + 1 < T_STEPS) ? t + 1 : t;
      xpre = ((const float2*)(xbase + tn * 2048))[tid];  // prefetch t+1 (latency hidden)
    }

    // ---- phase 2: conv1 (folded 6x6, stride2) + BN + LIF; one row per wave ----
    if (wave < 14) {
      const int py = wave;
      float acc[14];
      #pragma unroll
      for (int p = 0; p < 14; ++p) acc[p] = 0.f;
      const float* xr = &sm[L_XT + ic1 * 1024 + py * 64];
      #pragma unroll
      for (int r = 0; r < 6; ++r) {
        float row[32];
        const float4* rp = (const float4*)&xr[r * 32];
        #pragma unroll
        for (int q = 0; q < 8; ++q) {
          float4 f = rp[q];
          row[4*q] = f.x; row[4*q+1] = f.y; row[4*q+2] = f.z; row[4*q+3] = f.w;
        }
        #pragma unroll
        for (int v = 0; v < 6; ++v) {
          float wv = w1r[r * 6 + v];
          #pragma unroll
          for (int px = 0; px < 14; ++px) acc[px] += row[2*px + v] * wv;
        }
      }
      #pragma unroll
      for (int px = 0; px < 14; ++px) acc[px] += __shfl_xor(acc[px], 1);
      if (ic1 == 0) {
        float flag = 0.f;
        #pragma unroll
        for (int px = 0; px < 14; ++px) {
          float c = acc[px] * s1v + sh1v;
          const int vidx = L_VC1 + (py * 14 + px) * 32 + oc1;
          float vold = sm[vidx];
          float v = b1v * vold + (1.f - b1v) * c;
          float s = (v > 1.f) ? 1.f : 0.f;
          sm[vidx] = v * (1.f - s);
          sm[L_SPK1 + oc1 * 228 + py * 16 + px] = s;
          flag += s;
        }
        sm[L_FLAG + oc1 * 14 + py] = flag;
      }
    }
    if (tid == 0) *cntI = 0;
    __syncthreads();                                     // barrier B

    // ---- phase 3: conv2; wave=(g,h): g -> 4 ic planes, h -> py half ----
    {
      const int g = wave & 7, h = wave >> 3;
      float acc[15];
      #pragma unroll
      for (int p = 0; p < 15; ++p) acc[p] = 0.f;
      if (h == 0) {
        CONV2_BODY(0, 7, 0, 2)          // py 0..2 (15 outputs), rows iy 0..7
      } else {
        CONV2_BODY(6, 13, 3, 4)         // py 3..4 (10 outputs), rows iy 6..13
      }
      // disjoint slices of RED[g]: h=0 -> p 0..14, h=1 -> p 15..24
      if (h == 0) {
        #pragma unroll
        for (int p = 0; p < 15; ++p) sm[L_RED + g * 1600 + lane * 25 + p] = acc[p];
      } else {
        #pragma unroll
        for (int p = 0; p < 10; ++p) sm[L_RED + g * 1600 + lane * 25 + 15 + p] = acc[p];
      }
    }
    __syncthreads();                                     // barrier C

    // ---- phase 4: reduce + BN + LIF -> spike list (ballot compaction) ----
    {
      #pragma unroll
      for (int k = 0; k < 2; ++k) {
        int n = tid + NT * k;
        float s = 0.f;
        if (n < 1600) {
          float ssum = 0.f;
          #pragma unroll
          for (int wv = 0; wv < 8; ++wv) ssum += sm[L_RED + wv * 1600 + n];
          int oc = n / 25;
          float c2 = ssum * sm[L_BN2 + oc] + sm[L_BN2 + 64 + oc];
          float b2 = sm[L_BN2 + 128 + oc];
          const int vidx = L_VC2 + n;
          float vold = sm[vidx];
          float v = b2 * vold + (1.f - b2) * c2;
          s = (v > 1.f) ? 1.f : 0.f;
          sm[vidx] = v * (1.f - s);
        }
        unsigned long long mask = __ballot(s > 0.f);
        if (mask) {
          int base = 0;
          if (lane == 0) base = atomicAdd(cntI, __popcll(mask));
          base = __shfl(base, 0);
          if (s > 0.f) {
            int pos = __popcll(mask & ((1ull << lane) - 1ull));
            listI[base + pos] = n;
          }
        }
      }
    }
    __syncthreads();                                     // barrier D

    // ---- phase 5: fc1 = sparse gather, float4/lane, 16-way wave split, 4 accumulators ----
    {
      const int j4 = lane;           // float4 column index
      const int h  = wave;
      const int nn = *cntI;
      const float4* fc4 = (const float4*)fc1T;
      float4 a0 = {0.f,0.f,0.f,0.f}, a1 = {0.f,0.f,0.f,0.f};
      float4 a2 = {0.f,0.f,0.f,0.f}, a3 = {0.f,0.f,0.f,0.f};
      int i = h;
      for (; i + 48 < nn; i += 64) {
        int k0 = listI[i], k1 = listI[i + 16], k2 = listI[i + 32], k3 = listI[i + 48];
        float4 f0 = fc4[k0 * 64 + j4];
        float4 f1 = fc4[k1 * 64 + j4];
        float4 f2 = fc4[k2 * 64 + j4];
        float4 f3 = fc4[k3 * 64 + j4];
        a0.x += f0.x; a0.y += f0.y; a0.z += f0.z; a0.w += f0.w;
        a1.x += f1.x; a1.y += f1.y; a1.z += f1.z; a1.w += f1.w;
        a2.x += f2.x; a2.y += f2.y; a2.z += f2.z; a2.w += f2.w;
        a3.x += f3.x; a3.y += f3.y; a3.z += f3.z; a3.w += f3.w;
      }
      for (; i < nn; i += 16) {
        int k = listI[i];
        float4 f = fc4[k * 64 + j4];
        a0.x += f.x; a0.y += f.y; a0.z += f.z; a0.w += f.w;
      }
      a0.x += a1.x + a2.x + a3.x;
      a0.y += a1.y + a2.y + a3.y;
      a0.z += a1.z + a2.z + a3.z;
      a0.w += a1.w + a2.w + a3.w;
      ((float4*)&sm[L_IPART2])[h * 64 + j4] = a0;
    }
    __syncthreads();                                     // barrier E

    // ---- phases 6-8 (wave 0 only): fc adaptive LIF, fc_out, output integrator ----
    // Neuron ownership j = lane + 64k (stride-1 accesses, conflict-free).
    // No trailing barrier: next step's barrier A orders IPART2/LIST reuse.
    if (wave == 0) {
      float s[4];
      #pragma unroll
      for (int k = 0; k < 4; ++k) {
        int j = lane + 64 * k;
        float I = 0.f;
        #pragma unroll
        for (int h2 = 0; h2 < 16; ++h2) I += sm[L_IPART2 + h2 * 256 + j];
        float al = sm[L_FCP + j], rh = sm[L_FCP + 256 + j], ba = sm[L_FCP + 512 + j];
        float vf = sm[L_FCS + j], af = sm[L_FCS + 256 + j], sp0 = sm[L_FCS + 512 + j];
        af = rh * af + (1.f - rh) * sp0;
        float v = al * vf + (1.f - al) * I;
        float sp = (v > 1.f + ba * af) ? 1.f : 0.f;
        sm[L_FCS + j] = v * (1.f - sp);
        sm[L_FCS + 256 + j] = af;
        sm[L_FCS + 512 + j] = sp;
        s[k] = sp;
      }
      float p[11];
      #pragma unroll
      for (int o = 0; o < 11; ++o) {
        p[o] = 0.f;
        #pragma unroll
        for (int k = 0; k < 4; ++k)
          p[o] += s[k] * sm[L_WOUT + o * 256 + lane + 64 * k];
      }
      #pragma unroll
      for (int m = 1; m < 64; m <<= 1)
        #pragma unroll
        for (int o = 0; o < 11; ++o) p[o] += __shfl_xor(p[o], m);
      float Isel = p[0];
      #pragma unroll
      for (int o = 1; o < 11; ++o) Isel = (lane == o) ? p[o] : Isel;
      if (lane < 11) {
        v_out = beta_o * v_out + (1.f - beta_o) * Isel;
        o_sum += v_out;
      }
    }
  }

  if (wave == 0 && lane < 11) out[b * 11 + lane] = o_sum * (1.f / T_STEPS);
}

extern "C" void kernel_launch(void* const* d_in, const int* in_sizes, int n_in,
                              void* d_out, int out_size, void* d_ws, size_t ws_size,
                              hipStream_t stream) {
  const float* x            = (const float*)d_in[0];
  const float* conv1_w      = (const float*)d_in[1];
  const float* bn1_gamma    = (const float*)d_in[2];
  const float* bn1_beta     = (const float*)d_in[3];
  const float* bn1_mean     = (const float*)d_in[4];
  const float* bn1_var      = (const float*)d_in[5];
  const float* conv2_w      = (const float*)d_in[6];
  const float* bn2_gamma    = (const float*)d_in[7];
  const float* bn2_beta     = (const float*)d_in[8];
  const float* bn2_mean     = (const float*)d_in[9];
  const float* bn2_var      = (const float*)d_in[10];
  const float* beta_c1_raw  = (const float*)d_in[11];
  const float* beta_c2_raw  = (const float*)d_in[12];
  const float* fc1_w        = (const float*)d_in[13];
  const float* alpha_raw    = (const float*)d_in[14];
  const float* rho_raw      = (const float*)d_in[15];
  const float* beta_a_p     = (const float*)d_in[16];
  const float* fc_out_w     = (const float*)d_in[17];
  const float* beta_out_p   = (const float*)d_in[18];
  float* ws  = (float*)d_ws;
  float* outp = (float*)d_out;

  (void)in_sizes; (void)n_in; (void)out_size; (void)ws_size;

  hipFuncSetAttribute((const void*)snn_kernel,
                      hipFuncAttributeMaxDynamicSharedMemorySize, SMEM_BYTES);

  prep_kernel<<<dim3((WS_TOTAL + 255) / 256), dim3(256), 0, stream>>>(
      conv1_w, conv2_w, fc1_w, ws);

  snn_kernel<<<dim3(128), dim3(NT), SMEM_BYTES, stream>>>(
      x, bn1_gamma, bn1_beta, bn1_mean, bn1_var,
      bn2_gamma, bn2_beta, bn2_mean, bn2_var,
      beta_c1_raw, beta_c2_raw, alpha_raw, rho_raw, beta_a_p,
      fc_out_w, beta_out_p, ws, outp);
}

// Round 4
// 1659.335 us; speedup vs baseline: 1.2825x; 1.2825x over previous
//
#include <hip/hip_runtime.h>
#include <math.h>

#define T_STEPS 50
#define NT 512

// workspace layout (float offsets)
#define WS_FC1T 0          // 1600*256 = 409600  : fc1_w transposed [k][j]
#define WS_W2F  409600     // 32*9*64*4 = 73728  : folded conv2, tap-quad-major [ic][q][oc][4]
#define WS_W1F  483328     // 36*64    = 2304    : folded conv1 [j][oc*2+ic]
#define WS_XDATA 485632    // 128*2*2*256 = 131072 : fc1 partial-I exchange, [item][half][parity][256]
#define WS_XFLG  616704    // 256 ints : per-(item,half) step flags
#define WS_XTOT  616960
#define WS_TOTAL 485632    // prep weight section end

// LDS layout (float offsets)
#define L_XT    0          // 2048
#define L_SPK1  2048       // 32 planes, stride 228 = 7296
#define L_RED   9344       // 8*1600 = 12800
#define L_WOUT  22144      // 2816
#define L_LIST  24960      // 800 (ints) : local spike list (this block's 800 neurons)
#define L_FLAG  25760      // 448
#define L_CNT   26208      // 16 (pad)
#define L_VC1   26224      // 6272 : conv1 membrane, [py*14+px]*32 + oc
#define L_VC2   32496      // 800 : local conv2 membrane
#define L_BN2   33296      // 192 : s2 | sh2 | b2
#define L_IPART2 33488     // 2048 : fc1 partials, 8 waves x 256
#define L_FCP   35536      // 768 : alpha | rho | beta_a (256 each)
#define L_FCS   36304      // 768 : vfc | afc | spf (256 each)
#define L_ILOC  37072      // 256 : this block's summed fc1 partial
#define L_TOTALF 37328     // 149312 B <= 163840 (160 KiB) -> 1 WG/CU
#define SMEM_BYTES (L_TOTALF * 4)

__global__ void prep_kernel(const float* __restrict__ conv1_w,
                            const float* __restrict__ conv2_w,
                            const float* __restrict__ fc1_w,
                            float* __restrict__ ws) {
  int i = blockIdx.x * blockDim.x + threadIdx.x;
  if (i < 409600) {
    int k = i >> 8, j = i & 255;
    ws[WS_FC1T + i] = fc1_w[j * 1600 + k];
  } else if (i < 409600 + 73728) {
    // tap-quad-major layout: index = ((ic*9 + q)*64 + oc)*4 + r, tap jj = 4q + r.
    int i2 = i - 409600;
    int r  = i2 & 3;
    int t2 = i2 >> 2;
    int oc = t2 & 63;
    int t3 = t2 >> 6;      // ic*9 + q
    int q  = t3 % 9;
    int ic = t3 / 9;
    int jj = q * 4 + r, u = jj / 6, v = jj % 6;
    float s = 0.f;
    for (int dy = 0; dy < 2; ++dy) {
      int ky = u - dy; if (ky < 0 || ky > 4) continue;
      for (int dx = 0; dx < 2; ++dx) {
        int kx = v - dx; if (kx < 0 || kx > 4) continue;
        s += conv2_w[((oc * 32 + ic) * 5 + ky) * 5 + kx];
      }
    }
    ws[WS_W2F + i2] = 0.25f * s;
  } else if (i < WS_TOTAL) {
    int i3 = i - 483328;
    int jj = i3 >> 6, l = i3 & 63, oc = l >> 1, ic = l & 1, u = jj / 6, v = jj % 6;
    float s = 0.f;
    for (int dy = 0; dy < 2; ++dy) {
      int ky = u - dy; if (ky < 0 || ky > 4) continue;
      for (int dx = 0; dx < 2; ++dx) {
        int kx = v - dx; if (kx < 0 || kx > 4) continue;
        s += conv1_w[((oc * 2 + ic) * 5 + ky) * 5 + kx];
      }
    }
    ws[WS_W1F + i3] = 0.25f * s;
  } else if (i >= WS_XFLG && i < WS_XTOT) {
    // step flags MUST start at 0 every launch; graph replay re-runs prep, so
    // this also resets state between replays.
    ((int*)ws)[i] = 0;
  }
}

// Pair-split: blocks (i, i+128) co-process batch item i&127 (1 block/CU, 256 CUs).
// Both redundantly compute conv1 (identical bitwise); each computes conv2 for its
// 32 oc, local LIF+spike list, fc1 gather over local spikes; then they exchange
// 256-float partial currents through ws with a release/acquire flag handshake.
// fc/out LIF is computed redundantly from the same sum (commutative add ->
// bitwise-identical state in both blocks); only half=0 writes out.
__global__ __launch_bounds__(NT, 2) void snn_kernel(
    const float* __restrict__ x,
    const float* __restrict__ bn1_gamma, const float* __restrict__ bn1_beta,
    const float* __restrict__ bn1_mean,  const float* __restrict__ bn1_var,
    const float* __restrict__ bn2_gamma, const float* __restrict__ bn2_beta,
    const float* __restrict__ bn2_mean,  const float* __restrict__ bn2_var,
    const float* __restrict__ beta_c1_raw, const float* __restrict__ beta_c2_raw,
    const float* __restrict__ alpha_raw, const float* __restrict__ rho_raw,
    const float* __restrict__ beta_a_p,  const float* __restrict__ fc_out_w,
    const float* __restrict__ beta_out_p,
    float* __restrict__ ws, float* __restrict__ out)
{
  extern __shared__ float sm[];
  int* listI = (int*)&sm[L_LIST];
  int* cntI  = (int*)&sm[L_CNT];
  const int tid = threadIdx.x, wave = tid >> 6, lane = tid & 63;
  const int b = blockIdx.x;
  const int half = b >> 7;          // 0: oc 0-31, 1: oc 32-63
  const int item = b & 127;         // batch index; partner block = b ^ 128 (same XCD)

  // exchange pointers
  float* xdW = ws + WS_XDATA + (size_t)(item * 2 + half) * 512;
  float* xdR = ws + WS_XDATA + (size_t)(item * 2 + (1 - half)) * 512;
  int* flgW = (int*)ws + WS_XFLG + item * 2 + half;
  int* flgR = (int*)ws + WS_XFLG + item * 2 + (1 - half);

  // one-time LDS staging + state zero-init
  for (int i = tid; i < 2816; i += NT) sm[L_WOUT + i] = fc_out_w[i];
  for (int i = tid; i < 6272; i += NT) sm[L_VC1 + i] = 0.f;
  for (int i = tid; i < 800; i += NT) sm[L_VC2 + i] = 0.f;
  if (tid < 256) {
    // fc params+state in LDS: only wave 0 touches them after init.
    sm[L_FCP + tid]       = 1.f / (1.f + expf(-alpha_raw[tid]));
    sm[L_FCP + 256 + tid] = 1.f / (1.f + expf(-rho_raw[tid]));
    sm[L_FCP + 512 + tid] = beta_a_p[tid];
    sm[L_FCS + tid] = 0.f;
    sm[L_FCS + 256 + tid] = 0.f;
    sm[L_FCS + 512 + tid] = 0.f;
  }
  if (tid < 64) {
    float s2 = bn2_gamma[tid] / sqrtf(bn2_var[tid] + 1e-5f);
    sm[L_BN2 + tid]       = s2;
    sm[L_BN2 + 64 + tid]  = bn2_beta[tid] - bn2_mean[tid] * s2;
    sm[L_BN2 + 128 + tid] = 1.f / (1.f + expf(-beta_c2_raw[tid]));
  }

  // conv1 lane mapping: lane = oc*2 + ic
  const int oc1 = lane >> 1, ic1 = lane & 1;
  const float s1v  = bn1_gamma[oc1] / sqrtf(bn1_var[oc1] + 1e-5f);
  const float sh1v = bn1_beta[oc1] - bn1_mean[oc1] * s1v;
  const float b1v  = 1.f / (1.f + expf(-beta_c1_raw[oc1]));
  const float beta_o = 1.f / (1.f + expf(-beta_out_p[0]));

  // conv1 weights: persistent in registers (36 regs)
  float w1r[36];
  #pragma unroll
  for (int j = 0; j < 36; ++j) w1r[j] = ws[WS_W1F + j * 64 + lane];

  int pyBase, npy;
  if (wave < 6) { pyBase = wave * 2; npy = 2; } else { pyBase = 12 + (wave - 6); npy = 1; }

  float v_out = 0.f, o_sum = 0.f;  // wave0, lane<11

  const float* xbase = x + (size_t)item * T_STEPS * 2048;
  const float* w2f  = ws + WS_W2F;
  const float* fc1T = ws + WS_FC1T;

  float4 xpre = ((const float4*)xbase)[tid];   // prefetch t=0

  __syncthreads();

  for (int t = 0; t < T_STEPS; ++t) {
    // ---- phase 1: commit prefetched x_t to LDS ----
    ((float4*)&sm[L_XT])[tid] = xpre;
    __syncthreads();                                     // barrier A
    {
      int tn = (t + 1 < T_STEPS) ? t + 1 : t;
      xpre = ((const float4*)(xbase + tn * 2048))[tid];  // prefetch t+1 (latency hidden)
    }

    // ---- phase 2: conv1 (folded 6x6, stride2) + BN + LIF (redundant in both halves) ----
    for (int rr = 0; rr < npy; ++rr) {
      const int py = pyBase + rr;
      float acc[14];
      #pragma unroll
      for (int p = 0; p < 14; ++p) acc[p] = 0.f;
      const float* xr = &sm[L_XT + ic1 * 1024 + py * 64];
      #pragma unroll
      for (int r = 0; r < 6; ++r) {
        float row[32];
        const float4* rp = (const float4*)&xr[r * 32];
        #pragma unroll
        for (int q = 0; q < 8; ++q) {
          float4 f = rp[q];
          row[4*q] = f.x; row[4*q+1] = f.y; row[4*q+2] = f.z; row[4*q+3] = f.w;
        }
        #pragma unroll
        for (int v = 0; v < 6; ++v) {
          float wv = w1r[r * 6 + v];
          #pragma unroll
          for (int px = 0; px < 14; ++px) acc[px] += row[2*px + v] * wv;
        }
      }
      #pragma unroll
      for (int px = 0; px < 14; ++px) acc[px] += __shfl_xor(acc[px], 1);
      if (ic1 == 0) {
        float flag = 0.f;
        #pragma unroll
        for (int px = 0; px < 14; ++px) {
          float c = acc[px] * s1v + sh1v;
          const int vidx = L_VC1 + (py * 14 + px) * 32 + oc1;
          float vold = sm[vidx];
          float v = b1v * vold + (1.f - b1v) * c;
          float s = (v > 1.f) ? 1.f : 0.f;
          sm[vidx] = v * (1.f - s);
          sm[L_SPK1 + oc1 * 228 + py * 16 + px] = s;
          flag += s;
        }
        sm[L_FLAG + oc1 * 14 + py] = flag;
      }
    }
    if (tid == 0) *cntI = 0;
    __syncthreads();                                     // barrier B

    // ---- phase 3: conv2 for this half's 32 oc; wave covers ic = wave+8*(2*ib+s),
    //      s = lane>>5 (half-wave ic slots), lane&31 = local oc ----
    {
      const int s5 = lane >> 5;
      const int ocl = lane & 31;
      const int ocg = half * 32 + ocl;
      float acc[25];
      #pragma unroll
      for (int p = 0; p < 25; ++p) acc[p] = 0.f;
      #pragma unroll
      for (int ib = 0; ib < 2; ++ib) {
        const int ic = wave + 8 * (2 * ib + s5);
        const float* fl = &sm[L_FLAG + ic * 14];
        float flg[14]; float fsum = 0.f;
        #pragma unroll
        for (int iy = 0; iy < 14; ++iy) { flg[iy] = fl[iy]; fsum += flg[iy]; }
        if (fsum != 0.f) {               // skip dead input planes (per half-wave)
          float w[36];
          {
            // tap-quad-major: per-lane (ic, ocg) -> two 512B segments per wave-load
            const float4* wp = ((const float4*)w2f) + (ic * 9) * 64 + ocg;
            #pragma unroll
            for (int q = 0; q < 9; ++q) {
              float4 f = wp[q * 64];
              w[4*q] = f.x; w[4*q+1] = f.y; w[4*q+2] = f.z; w[4*q+3] = f.w;
            }
          }
          const float* srow = &sm[L_SPK1 + ic * 228];
          #pragma unroll
          for (int iy = 0; iy < 14; ++iy) {
            if (flg[iy] != 0.f) {
              float row[16];
              const float4* rp = (const float4*)&srow[iy * 16];
              #pragma unroll
              for (int q = 0; q < 4; ++q) {
                float4 f = rp[q];
                row[4*q] = f.x; row[4*q+1] = f.y; row[4*q+2] = f.z; row[4*q+3] = f.w;
              }
              #pragma unroll
              for (int py = 0; py < 5; ++py) {
                const int u = iy - 2 * py;
                if (u >= 0 && u <= 5) {
                  #pragma unroll
                  for (int v = 0; v < 6; ++v) {
                    float wv = w[u * 6 + v];
                    #pragma unroll
                    for (int px = 0; px < 5; ++px) acc[py * 5 + px] += row[2*px + v] * wv;
                  }
                }
              }
            }
          }
        }
      }
      #pragma unroll
      for (int p = 0; p < 25; ++p) sm[L_RED + wave * 1600 + lane * 25 + p] = acc[p];
    }
    __syncthreads();                                     // barrier C

    // ---- phase 4: reduce (8 waves x 2 slots) + BN + LIF -> local spike list ----
    {
      #pragma unroll
      for (int k = 0; k < 2; ++k) {
        int n = tid + NT * k;          // local neuron 0..799 (slot = ocl*25+p)
        float s = 0.f;
        if (n < 800) {
          float ssum = 0.f;
          #pragma unroll
          for (int wv = 0; wv < 8; ++wv)
            ssum += sm[L_RED + wv * 1600 + n] + sm[L_RED + wv * 1600 + 800 + n];
          int ocg = half * 32 + n / 25;
          float c2 = ssum * sm[L_BN2 + ocg] + sm[L_BN2 + 64 + ocg];
          float b2 = sm[L_BN2 + 128 + ocg];
          const int vidx = L_VC2 + n;
          float vold = sm[vidx];
          float v = b2 * vold + (1.f - b2) * c2;
          s = (v > 1.f) ? 1.f : 0.f;
          sm[vidx] = v * (1.f - s);
        }
        unsigned long long mask = __ballot(s > 0.f);
        if (mask) {
          int base = 0;
          if (lane == 0) base = atomicAdd(cntI, __popcll(mask));
          base = __shfl(base, 0);
          if (s > 0.f) {
            int pos = __popcll(mask & ((1ull << lane) - 1ull));
            listI[base + pos] = half * 800 + n;   // GLOBAL neuron index for fc1T
          }
        }
      }
    }
    __syncthreads();                                     // barrier D

    // ---- phase 5: fc1 partial = gather over LOCAL spikes, float4/lane, 8-way split ----
    {
      const int j4 = tid & 63;       // float4 column index
      const int h  = tid >> 6;       // == wave
      const int nn = *cntI;
      const float4* fc4 = (const float4*)fc1T;
      float4 a0 = {0.f,0.f,0.f,0.f}, a1 = {0.f,0.f,0.f,0.f};
      float4 a2 = {0.f,0.f,0.f,0.f}, a3 = {0.f,0.f,0.f,0.f};
      int i = h;
      for (; i + 24 < nn; i += 32) {
        int k0 = listI[i], k1 = listI[i + 8], k2 = listI[i + 16], k3 = listI[i + 24];
        float4 f0 = fc4[k0 * 64 + j4];
        float4 f1 = fc4[k1 * 64 + j4];
        float4 f2 = fc4[k2 * 64 + j4];
        float4 f3 = fc4[k3 * 64 + j4];
        a0.x += f0.x; a0.y += f0.y; a0.z += f0.z; a0.w += f0.w;
        a1.x += f1.x; a1.y += f1.y; a1.z += f1.z; a1.w += f1.w;
        a2.x += f2.x; a2.y += f2.y; a2.z += f2.z; a2.w += f2.w;
        a3.x += f3.x; a3.y += f3.y; a3.z += f3.z; a3.w += f3.w;
      }
      for (; i < nn; i += 8) {
        int k = listI[i];
        float4 f = fc4[k * 64 + j4];
        a0.x += f.x; a0.y += f.y; a0.z += f.z; a0.w += f.w;
      }
      a0.x += a1.x + a2.x + a3.x;
      a0.y += a1.y + a2.y + a3.y;
      a0.z += a1.z + a2.z + a3.z;
      a0.w += a1.w + a2.w + a3.w;
      ((float4*)&sm[L_IPART2])[h * 64 + j4] = a0;
    }
    __syncthreads();                                     // barrier E

    // ---- exchange: publish local partial I (256 floats, parity-buffered) ----
    if (tid < 256) {
      float I = 0.f;
      #pragma unroll
      for (int h2 = 0; h2 < 8; ++h2) I += sm[L_IPART2 + h2 * 256 + tid];
      sm[L_ILOC + tid] = I;
      __hip_atomic_store(&xdW[(t & 1) * 256 + tid], I,
                         __ATOMIC_RELAXED, __HIP_MEMORY_SCOPE_AGENT);
    }
    __syncthreads();                                     // barrier F (drains stores)
    if (tid == 0) {
      __threadfence();
      __hip_atomic_store(flgW, t + 1, __ATOMIC_RELEASE, __HIP_MEMORY_SCOPE_AGENT);
    }

    // ---- phases 6-8 (wave 0 only): wait for partner, fc LIF, fc_out, integrator ----
    // Waves 1-7 run ahead into next step's phase 1 and wait at barrier A.
    if (wave == 0) {
      while (__hip_atomic_load(flgR, __ATOMIC_ACQUIRE, __HIP_MEMORY_SCOPE_AGENT) < t + 1) {
        __builtin_amdgcn_s_sleep(1);
      }
      float s[4];
      #pragma unroll
      for (int k = 0; k < 4; ++k) {
        int j = lane + 64 * k;
        float I = sm[L_ILOC + j] +
                  __hip_atomic_load(&xdR[(t & 1) * 256 + j],
                                    __ATOMIC_RELAXED, __HIP_MEMORY_SCOPE_AGENT);
        float al = sm[L_FCP + j], rh = sm[L_FCP + 256 + j], ba = sm[L_FCP + 512 + j];
        float vf = sm[L_FCS + j], af = sm[L_FCS + 256 + j], sp0 = sm[L_FCS + 512 + j];
        af = rh * af + (1.f - rh) * sp0;
        float v = al * vf + (1.f - al) * I;
        float sp = (v > 1.f + ba * af) ? 1.f : 0.f;
        sm[L_FCS + j] = v * (1.f - sp);
        sm[L_FCS + 256 + j] = af;
        sm[L_FCS + 512 + j] = sp;
        s[k] = sp;
      }
      float p[11];
      #pragma unroll
      for (int o = 0; o < 11; ++o) {
        p[o] = 0.f;
        #pragma unroll
        for (int k = 0; k < 4; ++k)
          p[o] += s[k] * sm[L_WOUT + o * 256 + lane + 64 * k];
      }
      #pragma unroll
      for (int m = 1; m < 64; m <<= 1)
        #pragma unroll
        for (int o = 0; o < 11; ++o) p[o] += __shfl_xor(p[o], m);
      float Isel = p[0];
      #pragma unroll
      for (int o = 1; o < 11; ++o) Isel = (lane == o) ? p[o] : Isel;
      if (lane < 11) {
        v_out = beta_o * v_out + (1.f - beta_o) * Isel;
        o_sum += v_out;
      }
    }
  }

  if (half == 0 && wave == 0 && lane < 11) out[item * 11 + lane] = o_sum * (1.f / T_STEPS);
}

extern "C" void kernel_launch(void* const* d_in, const int* in_sizes, int n_in,
                              void* d_out, int out_size, void* d_ws, size_t ws_size,
                              hipStream_t stream) {
  const float* x            = (const float*)d_in[0];
  const float* conv1_w      = (const float*)d_in[1];
  const float* bn1_gamma    = (const float*)d_in[2];
  const float* bn1_beta     = (const float*)d_in[3];
  const float* bn1_mean     = (const float*)d_in[4];
  const float* bn1_var      = (const float*)d_in[5];
  const float* conv2_w      = (const float*)d_in[6];
  const float* bn2_gamma    = (const float*)d_in[7];
  const float* bn2_beta     = (const float*)d_in[8];
  const float* bn2_mean     = (const float*)d_in[9];
  const float* bn2_var      = (const float*)d_in[10];
  const float* beta_c1_raw  = (const float*)d_in[11];
  const float* beta_c2_raw  = (const float*)d_in[12];
  const float* fc1_w        = (const float*)d_in[13];
  const float* alpha_raw    = (const float*)d_in[14];
  const float* rho_raw      = (const float*)d_in[15];
  const float* beta_a_p     = (const float*)d_in[16];
  const float* fc_out_w     = (const float*)d_in[17];
  const float* beta_out_p   = (const float*)d_in[18];
  float* ws  = (float*)d_ws;
  float* outp = (float*)d_out;

  (void)in_sizes; (void)n_in; (void)out_size; (void)ws_size;

  hipFuncSetAttribute((const void*)snn_kernel,
                      hipFuncAttributeMaxDynamicSharedMemorySize, SMEM_BYTES);

  prep_kernel<<<dim3((WS_XTOT + 255) / 256), dim3(256), 0, stream>>>(
      conv1_w, conv2_w, fc1_w, ws);

  snn_kernel<<<dim3(256), dim3(NT), SMEM_BYTES, stream>>>(
      x, bn1_gamma, bn1_beta, bn1_mean, bn1_var,
      bn2_gamma, bn2_beta, bn2_mean, bn2_var,
      beta_c1_raw, beta_c2_raw, alpha_raw, rho_raw, beta_a_p,
      fc_out_w, beta_out_p, ws, outp);
}